// Round 9
// baseline (71.966 us; speedup 1.0000x reference)
//
#include <hip/hip_runtime.h>
#include <hip/hip_bf16.h>

#define NB 16
#define NC 4
#define NL 4096
#define NK 256
#define NS 128
#define NW (NL - NS + 1)           /* 3969 */
#define WPB 512                    /* windows per block (one supertask) */
#define KPB 128                    /* k per block (K split 2-way by blockIdx.x) */
#define XEL 640                    /* staged x elements per channel (511+128+1) */
#define XROW 656                   /* xcp row stride: 1312 B = 8-bank step/row */
#define EPSF 1e-8f

typedef __attribute__((ext_vector_type(8))) _Float16 f16x8;
typedef __attribute__((ext_vector_type(2))) _Float16 f16x2;
typedef __attribute__((ext_vector_type(4))) float floatx4;

typedef __attribute__((address_space(3))) unsigned int* lds_ptr_t;
typedef const __attribute__((address_space(1))) unsigned int* gbl_ptr_t;

__device__ inline short f2h(float f) {
    _Float16 h = (_Float16)f;
    short s;
    __builtin_memcpy(&s, &h, sizeof(short));
    return s;
}

__device__ inline void gload_lds16(const void* g, void* l) {
    __builtin_amdgcn_global_load_lds((gbl_ptr_t)g, (lds_ptr_t)l, 16, 0, 0);
}

// K1: normalize shapelets (fp32 in), write fp16 bits PRE-SWIZZLED within each
// 256B row so the main kernel can global_load_lds linearly. One wave per (c,k).
__global__ __launch_bounds__(64)
void norm_shp_kernel(const float* __restrict__ shp, short* __restrict__ shpn) {
    int ck = blockIdx.x;
    int k = ck & (NK - 1);
    int lane = threadIdx.x;
    const float* p = shp + (size_t)ck * NS;
    float v0 = p[lane];
    float v1 = p[lane + 64];
    float ss = v0 * v0 + v1 * v1;
    #pragma unroll
    for (int o = 32; o > 0; o >>= 1) ss += __shfl_xor(ss, o, 64);
    float rn = 1.f / fmaxf(sqrtf(ss), EPSF);
    // swizzled element positions: 16B unit u of row k goes to unit u^(k&15)
    int s0 = lane, s1 = lane + 64;
    int d0 = ((((s0 >> 3) ^ (k & 15)) << 3) | (s0 & 7));
    int d1 = ((((s1 >> 3) ^ (k & 15)) << 3) | (s1 & 7));
    shpn[(size_t)ck * NS + d0] = f2h(v0 * rn);
    shpn[(size_t)ck * NS + d1] = f2h(v1 * rn);
}

// K2: 512-thread supertask kernel, software-pipelined compute. Grid =
// (kq=2, slot=128) = 256 blocks = 1/CU, 8 waves. Compute: 16 (c,s0) iters
// split into half-iters (mt groups of 4); each half-iter prefetches the next
// group's A fragments under 16 MFMAs, B double-buffered at iter grain, invw
// scaling on the consume side so waits land after a full MFMA shadow.
// setprio(1) around MFMA clusters (barrier-free burst -> waves drift).
__global__ __launch_bounds__(512, 1)
void mcs_main_kernel(const float* __restrict__ x,
                     const short* __restrict__ shpn,
                     float* __restrict__ out) {
    __shared__ f16x8 bs[NC][KPB * 16];             // 128 KB swizzled B
    __shared__ alignas(16) short xcp[NC][4][XROW]; // 20.5 KB shifted fp16 x
    __shared__ union {
        float scratch[NC][XEL];                    // prologue: x^2 -> prefix
        struct { float invw[NC][WPB]; float epi[8][64]; } c;
    } u;                                           // 10.25 KB

    const int kq = blockIdx.x, slot = blockIdx.y;
    const int b = slot >> 3, wslot = slot & 7;
    const int w0 = wslot * WPB;
    const int tid = threadIdx.x;
    const int lane = tid & 63, wv = tid >> 6;
    const int m = lane & 15, q = lane >> 4, r = m & 3;
    const int kh = wv & 1, wh = wv >> 1;

    // ---- B staging: ONCE per block, 128 KB, zero VGPR / zero VALU,
    // in flight over the entire prologue. ----
    {
        const char* gbase = (const char*)shpn + (size_t)(kq * KPB) * NS * 2;
        #pragma unroll
        for (int c = 0; c < NC; c++) {
            const char* gc = gbase + (size_t)c * NK * NS * 2;
            char* lc = (char*)&bs[c][0];
            #pragma unroll
            for (int i = 0; i < 4; i++) {
                int off = (wv * 4 + i) * 1024;
                gload_lds16(gc + off + lane * 16, lc + off);
            }
        }
    }

    // ---- x into regs: thread tid holds elements tid and (tid<128) tid+512 --
    float xv[NC], xv2[NC];
    {
        const int g0 = w0 + tid;
        #pragma unroll
        for (int c = 0; c < NC; c++)
            xv[c] = (g0 < NL) ? x[((size_t)b * NC + c) * NL + g0] : 0.f;
        if (tid < XEL - 512) {
            const int g1 = g0 + 512;
            #pragma unroll
            for (int c = 0; c < NC; c++)
                xv2[c] = (g1 < NL) ? x[((size_t)b * NC + c) * NL + g1] : 0.f;
        }
    }

    // ---- stage x: shift-copies (raw fp16) + squares ----
    #pragma unroll
    for (int c = 0; c < NC; c++) {
        short hv = f2h(xv[c]);
        #pragma unroll
        for (int rr = 0; rr < 4; rr++) {
            int o2 = tid - rr;
            if (o2 >= 0) xcp[c][rr][o2] = hv;       // xcp[c][r][o] = x[o+r]
        }
        u.scratch[c][tid] = xv[c] * xv[c];
        if (tid < XEL - 512) {
            short hv2 = f2h(xv2[c]);
            #pragma unroll
            for (int rr = 0; rr < 4; rr++)
                xcp[c][rr][tid + 512 - rr] = hv2;
            u.scratch[c][tid + 512] = xv2[c] * xv2[c];
        }
    }
    __syncthreads();

    // ---- inclusive prefix scan of x^2: wave c scans channel c (10/lane) ----
    if (wv < 4) {
        const int c = wv;
        const int base = lane * 10;
        float v[10];
        #pragma unroll
        for (int i = 0; i < 10; i++) v[i] = u.scratch[c][base + i];
        #pragma unroll
        for (int i = 1; i < 10; i++) v[i] += v[i - 1];
        float tt = v[9];
        #pragma unroll
        for (int o = 1; o < 64; o <<= 1) {
            float uu = __shfl_up(tt, o, 64);
            if (lane >= o) tt += uu;
        }
        float excl = tt - v[9];
        #pragma unroll
        for (int i = 0; i < 10; i++) u.scratch[c][base + i] = v[i] + excl;
    }
    __syncthreads();

    // ---- window inverse norms: scratch -> regs, barrier, aliased store ----
    float ivreg[4];
    #pragma unroll
    for (int i = 0; i < 4; i++) {
        int ii = tid + 512 * i;
        int c = ii >> 9, o = ii & 511;
        float nn = u.scratch[c][o + 127] - (o ? u.scratch[c][o - 1] : 0.f);
        int w = w0 + o;
        ivreg[i] = (w < NW) ? 1.f / fmaxf(sqrtf(fmaxf(nn, 0.f)), EPSF) : 0.f;
    }
    __syncthreads();   // all scratch reads complete before aliased writes
    #pragma unroll
    for (int i = 0; i < 4; i++) {
        int ii = tid + 512 * i;
        u.c.invw[ii >> 9][ii & 511] = ivreg[i];
    }
    asm volatile("s_waitcnt vmcnt(0)" ::: "memory");   // B staged
    __syncthreads();

    // ---- compute: software-pipelined burst, zero global ops, zero barriers --
    floatx4 tot[8][4];
    #pragma unroll
    for (int mt = 0; mt < 8; mt++)
        #pragma unroll
        for (int kt = 0; kt < 4; kt++)
            tot[mt][kt] = (floatx4){0.f, 0.f, 0.f, 0.f};

    f16x8 aA[4], aB[4], bA[4], bB[4];
    f16x2 iv[8];

    auto loadIv = [&](int c) {
        #pragma unroll
        for (int mt = 0; mt < 8; mt++) {
            _Float16 ih = (_Float16)u.c.invw[c][wh * 128 + mt * 16 + m];
            iv[mt] = (f16x2){ih, ih};
        }
    };
    auto loadA4 = [&](int c, int s0, int g, f16x8* a) {   // mt group g: 4 frags
        #pragma unroll
        for (int i = 0; i < 4; i++) {
            int mt = g * 4 + i;
            int ts = wh * 128 + mt * 16 + m + s0 + q * 8;
            const uint2* pp = (const uint2*)&xcp[c][r][ts - r];
            union { uint2 uu[2]; f16x8 v; } cv;
            cv.uu[0] = pp[0]; cv.uu[1] = pp[1];
            a[i] = cv.v;                                   // RAW (scale deferred)
        }
    };
    auto loadB4 = [&](int c, int s0, f16x8* bv) {
        int cc = (s0 >> 3) + q;
        #pragma unroll
        for (int kt = 0; kt < 4; kt++) {
            int k = kh * 64 + kt * 16 + m;                 // k&15 == m
            bv[kt] = bs[c][(k << 4) | (cc ^ m)];
        }
    };
    auto mm16 = [&](int g, f16x8* a, f16x8* bv) {
        #pragma unroll
        for (int i = 0; i < 4; i++) {      // consume-side invw scale (pk_mul)
            union { f16x8 v; f16x2 h2[4]; } cv;
            cv.v = a[i];
            #pragma unroll
            for (int p2 = 0; p2 < 4; p2++) cv.h2[p2] *= iv[g * 4 + i];
            a[i] = cv.v;
        }
        __builtin_amdgcn_s_setprio(1);
        #pragma unroll
        for (int kt = 0; kt < 4; kt++)
            #pragma unroll
            for (int i = 0; i < 4; i++)
                tot[g * 4 + i][kt] = __builtin_amdgcn_mfma_f32_16x16x32_f16(
                    a[i], bv[kt], tot[g * 4 + i][kt], 0, 0, 0);
        __builtin_amdgcn_s_setprio(0);
    };

    loadIv(0);
    loadA4(0, 0, 0, aA);
    loadB4(0, 0, bA);
    #pragma unroll
    for (int ip = 0; ip < 8; ip++) {
        {   // even iteration: it = 2*ip; cur B = bA, next B -> bB
            const int it = 2 * ip, c = it >> 2, s0 = (it & 3) * 32;
            const int cn = (it + 1) >> 2, sn = ((it + 1) & 3) * 32;
            loadA4(c, s0, 1, aB);          // group1 of cur under mm16(0)
            mm16(0, aA, bA);
            loadA4(cn, sn, 0, aA);         // group0 of next under mm16(1)
            loadB4(cn, sn, bB);
            mm16(1, aB, bA);
        }
        {   // odd iteration: it = 2*ip+1; cur B = bB, next B -> bA
            const int it = 2 * ip + 1, c = it >> 2, s0 = (it & 3) * 32;
            const bool last = (it == 15);
            const int cn = last ? c : (it + 1) >> 2;
            const int sn = last ? s0 : ((it + 1) & 3) * 32;
            loadA4(c, s0, 1, aB);
            mm16(0, aA, bB);
            if (!last) { loadA4(cn, sn, 0, aA); loadB4(cn, sn, bA); }
            mm16(1, aB, bB);
            if ((it & 3) == 3 && !last) loadIv(cn);   // c boundary: it=3,7,11
        }
    }

    // ---- epilogue: wave-max over its 128 windows per k ----
    #pragma unroll
    for (int kt = 0; kt < 4; kt++) {
        float mx = -1e30f;
        #pragma unroll
        for (int mt = 0; mt < 8; mt++) {
            floatx4 v = tot[mt][kt];
            mx = fmaxf(mx, fmaxf(fmaxf(v.x, v.y), fmaxf(v.z, v.w)));
        }
        mx = fmaxf(mx, __shfl_xor(mx, 16, 64));
        mx = fmaxf(mx, __shfl_xor(mx, 32, 64));
        if (lane < 16) u.c.epi[wv][kt * 16 + lane] = mx;   // own row, no race
    }
    __syncthreads();
    if (tid < 128) {
        // k-local = tid; computed by the 4 wh-waves with kh = tid>>6
        int kh_ = tid >> 6, j = tid & 63;
        float v = fmaxf(fmaxf(u.c.epi[kh_][j],     u.c.epi[kh_ + 2][j]),
                        fmaxf(u.c.epi[kh_ + 4][j], u.c.epi[kh_ + 6][j]));
        v = fmaxf(v, 0.f) * 0.25f;    // ReLU + 1/C, nonneg -> int-monotonic
        atomicMax((int*)out + (size_t)b * NK + kq * KPB + tid,
                  __float_as_int(v));
    }
}

extern "C" void kernel_launch(void* const* d_in, const int* in_sizes, int n_in,
                              void* d_out, int out_size, void* d_ws, size_t ws_size,
                              hipStream_t stream) {
    (void)in_sizes; (void)n_in; (void)out_size; (void)ws_size;
    const float* x   = (const float*)d_in[0];
    const float* shp = (const float*)d_in[1];
    float* out = (float*)d_out;

    short* shpn = (short*)d_ws;     // 256 KB of workspace

    norm_shp_kernel<<<NC * NK, 64, 0, stream>>>(shp, shpn);
    mcs_main_kernel<<<dim3(2, 128), 512, 0, stream>>>(x, shpn, out);
}